// Round 3
// baseline (851.021 us; speedup 1.0000x reference)
//
#include <hip/hip_runtime.h>
#include <math.h>

#define BN 512
#define DN 256
#define KN 65536
#define CN 1000
#define EQ_CAP 512
#define EPSTR 136   // padded epilogue LDS stride (ushorts)

typedef __attribute__((ext_vector_type(8))) short bf16x8;
typedef __attribute__((ext_vector_type(4))) float f32x4;

__device__ __forceinline__ unsigned short f2bf(float f) {
    unsigned u = __float_as_uint(f);
    unsigned r = (u + 0x7FFFu + ((u >> 16) & 1u)) >> 16;
    return (unsigned short)r;
}
__device__ __forceinline__ float bf2f(unsigned short h) {
    return __uint_as_float(((unsigned)h) << 16);
}
__device__ __forceinline__ unsigned fkey16(unsigned b) {
    b &= 0xFFFFu;
    return (b & 0x8000u) ? ((~b) & 0xFFFFu) : (b | 0x8000u);
}
__device__ __forceinline__ void async16(const void* g, void* l) {
    __builtin_amdgcn_global_load_lds(
        (const __attribute__((address_space(1))) unsigned*)g,
        (__attribute__((address_space(3))) unsigned*)l, 16, 0, 0);
}
// packed f32x2 -> bf16x2 (RNE), single instruction; lo -> D[15:0]
__device__ __forceinline__ unsigned cvtpk(float lo, float hi) {
    unsigned r;
    asm("v_cvt_pk_bf16_f32 %0, %1, %2" : "=v"(r) : "v"(lo), "v"(hi));
    return r;
}

// ---- fp32 -> bf16 convert (norm_q / k_feat into Acat halves) ----
__global__ void __launch_bounds__(256) cvt_bf16(const float* __restrict__ in,
                                                unsigned short* __restrict__ out) {
    int i = (blockIdx.x * 256 + threadIdx.x) * 4;
    float4 v = *(const float4*)&in[i];
    ushort4 o;
    o.x = f2bf(v.x); o.y = f2bf(v.y); o.z = f2bf(v.z); o.w = f2bf(v.w);
    *(ushort4*)&out[i] = o;
}

// ---- queue [256,65536] f32 -> queueT [65536,256] bf16 ----
__global__ void __launch_bounds__(256) transpose_q(const float* __restrict__ Q,
                                                   unsigned short* __restrict__ Qt) {
    __shared__ float T[64][65];
    int tid = threadIdx.x;
    int n0 = blockIdx.x * 64;
    int d0 = blockIdx.y * 64;
    #pragma unroll
    for (int i = 0; i < 4; ++i) {
        int flat = i * 256 + tid;
        int d = flat >> 4, nq = (flat & 15) * 4;
        float4 v = *(const float4*)&Q[(size_t)(d0 + d) * KN + n0 + nq];
        T[d][nq] = v.x; T[d][nq + 1] = v.y; T[d][nq + 2] = v.z; T[d][nq + 3] = v.w;
    }
    __syncthreads();
    int n = tid >> 2, dbase = (tid & 3) * 16;
    unsigned u[8];
    #pragma unroll
    for (int j = 0; j < 8; ++j) {
        unsigned short a = f2bf(T[dbase + 2 * j][n]);
        unsigned short b = f2bf(T[dbase + 2 * j + 1][n]);
        u[j] = (unsigned)a | ((unsigned)b << 16);
    }
    unsigned short* o = &Qt[(size_t)(n0 + n) * DN + d0 + dbase];
    *(uint4*)o = make_uint4(u[0], u[1], u[2], u[3]);
    *(uint4*)(o + 8) = make_uint4(u[4], u[5], u[6], u[7]);
}

// ---- MFMA GEMM, swapped operands, LDS-transposed coalesced epilogue.
// Blocks with blockIdx.y >= mBlockSplit apply exp(10x) and accumulate row sums.
__global__ void __launch_bounds__(256) gemm_sim(const unsigned short* __restrict__ A,
                                                const unsigned short* __restrict__ Bt,
                                                unsigned short* __restrict__ simOut,
                                                unsigned short* __restrict__ expOut,
                                                float* __restrict__ Zb,
                                                int mBlockSplit) {
    __shared__ unsigned short smem[128 * 64 * 2];   // As | Bs, reused as epilogue buf
    __shared__ float Zred[128];
    unsigned short* As = smem;
    unsigned short* Bs = smem + 128 * 64;
    int tid = threadIdx.x;
    int n0 = blockIdx.x * 128, m0 = blockIdx.y * 128;
    bool isExp = ((int)blockIdx.y >= mBlockSplit);
    int lane = tid & 63, w = tid >> 6;
    int l15 = lane & 15, quad = lane >> 4;
    int wm = w & 1, wn = w >> 1;
    f32x4 acc[4][4];   // [mi][ni]; D layout: col(l15)=m, row(quad*4+reg)=n
    #pragma unroll
    for (int mi = 0; mi < 4; ++mi)
        #pragma unroll
        for (int ni = 0; ni < 4; ++ni)
            #pragma unroll
            for (int j = 0; j < 4; ++j) acc[mi][ni][j] = 0.f;

    for (int k0 = 0; k0 < DN; k0 += 64) {
        #pragma unroll
        for (int i = 0; i < 4; ++i) {
            int f = (i * 256 + tid) * 8;
            async16(A + (size_t)(m0 + (f >> 6)) * DN + k0 + (f & 63), &As[f]);
        }
        #pragma unroll
        for (int i = 0; i < 4; ++i) {
            int f = (i * 256 + tid) * 8;
            async16(Bt + (size_t)(n0 + (f >> 6)) * DN + k0 + (f & 63), &Bs[f]);
        }
        __syncthreads();
        #pragma unroll
        for (int ks = 0; ks < 2; ++ks) {
            bf16x8 am[4], bn[4];
            #pragma unroll
            for (int mi = 0; mi < 4; ++mi)
                am[mi] = *(const bf16x8*)&As[(wm * 64 + mi * 16 + l15) * 64 + ks * 32 + quad * 8];
            #pragma unroll
            for (int ni = 0; ni < 4; ++ni)
                bn[ni] = *(const bf16x8*)&Bs[(wn * 64 + ni * 16 + l15) * 64 + ks * 32 + quad * 8];
            #pragma unroll
            for (int mi = 0; mi < 4; ++mi)
                #pragma unroll
                for (int ni = 0; ni < 4; ++ni)
                    acc[mi][ni] = __builtin_amdgcn_mfma_f32_16x16x32_bf16(bn[ni], am[mi], acc[mi][ni], 0, 0, 0);
        }
        __syncthreads();
    }

    unsigned short* obase = isExp ? expOut : simOut;
    int orow0 = isExp ? (m0 - mBlockSplit * 128) : m0;
    float rsum[4] = {0.f, 0.f, 0.f, 0.f};

    // two rounds of 64 rows each through padded LDS, then coalesced 16B stores
    #pragma unroll
    for (int round = 0; round < 2; ++round) {
        if (wm == round) {
            #pragma unroll
            for (int mi = 0; mi < 4; ++mi) {
                int mrow = mi * 16 + l15;   // within round
                #pragma unroll
                for (int ni = 0; ni < 4; ++ni) {
                    int nc = wn * 64 + ni * 16 + quad * 4;
                    float v0 = acc[mi][ni][0], v1 = acc[mi][ni][1];
                    float v2 = acc[mi][ni][2], v3 = acc[mi][ni][3];
                    if (isExp) {
                        v0 = __expf(v0 * 10.0f); v1 = __expf(v1 * 10.0f);
                        v2 = __expf(v2 * 10.0f); v3 = __expf(v3 * 10.0f);
                    }
                    unsigned short u0 = f2bf(v0), u1 = f2bf(v1), u2 = f2bf(v2), u3 = f2bf(v3);
                    if (isExp) rsum[mi] += bf2f(u0) + bf2f(u1) + bf2f(u2) + bf2f(u3);
                    *(uint2*)&smem[mrow * EPSTR + nc] =
                        make_uint2((unsigned)u0 | ((unsigned)u1 << 16),
                                   (unsigned)u2 | ((unsigned)u3 << 16));
                }
            }
        }
        __syncthreads();
        #pragma unroll
        for (int j = 0; j < 4; ++j) {
            int fc = j * 256 + tid;          // 0..1023
            int mr = fc >> 4;                // 0..63
            int ch = fc & 15;                // 16-byte chunk within row
            uint4 val = *(uint4*)&smem[mr * EPSTR + ch * 8];
            int g = orow0 + round * 64 + mr;
            *(uint4*)&obase[(size_t)g * KN + n0 + ch * 8] = val;
        }
        __syncthreads();
    }

    if (isExp) {
        float v4[4];
        #pragma unroll
        for (int mi = 0; mi < 4; ++mi) {
            float v = rsum[mi];
            v += __shfl_xor(v, 16, 64);
            v += __shfl_xor(v, 32, 64);
            v4[mi] = v;
        }
        if (wn == 0 && quad == 0) {
            #pragma unroll
            for (int mi = 0; mi < 4; ++mi) Zred[wm * 64 + mi * 16 + l15] = v4[mi];
        }
        __syncthreads();
        if (wn == 1 && quad == 0) {
            #pragma unroll
            for (int mi = 0; mi < 4; ++mi) Zred[wm * 64 + mi * 16 + l15] += v4[mi];
        }
        __syncthreads();
        if (tid < 128) atomicAdd(&Zb[orow0 + tid], Zred[tid]);
    }
}

// ---- supcon on bf16 sim: 2-pass radix select over 16-bit keys + fused loss ----
__global__ void __launch_bounds__(256) supcon(const unsigned short* __restrict__ sim,
                                              const int* __restrict__ qlabel,
                                              const int* __restrict__ target,
                                              const int* __restrict__ knnp,
                                              float* __restrict__ out0) {
    __shared__ unsigned hist[4][256];
    __shared__ unsigned s_sel, s_cntAbove;
    __shared__ int eqIdx[EQ_CAP];
    __shared__ unsigned eqCount;
    __shared__ float redZ[256], redN[256];
    int tid = threadIdx.x, w = tid >> 6;
    int row = blockIdx.x;
    const unsigned short* srow = sim + (size_t)row * KN;
    int knn = *knnp;
    int tgt = target[row];
    if (tid == 0) { eqCount = 0u; }
    #pragma unroll
    for (int j = 0; j < 4; ++j) hist[j][tid] = 0u;
    __syncthreads();
    for (int i0 = tid * 4; i0 < KN; i0 += 1024) {
        uint2 v = *(const uint2*)&srow[i0];
        atomicAdd(&hist[w][fkey16(v.x) >> 8], 1u);
        atomicAdd(&hist[w][fkey16(v.x >> 16) >> 8], 1u);
        atomicAdd(&hist[w][fkey16(v.y) >> 8], 1u);
        atomicAdd(&hist[w][fkey16(v.y >> 16) >> 8], 1u);
    }
    __syncthreads();
    if (tid == 0) {
        unsigned acc = 0; int chosen = 0;
        for (int bin = 255; bin >= 0; --bin) {
            unsigned h = hist[0][bin] + hist[1][bin] + hist[2][bin] + hist[3][bin];
            if (acc + h >= (unsigned)knn) { chosen = bin; break; }
            acc += h;
        }
        s_cntAbove = acc; s_sel = (unsigned)chosen;
    }
    __syncthreads();
    unsigned selHi = s_sel;
    #pragma unroll
    for (int j = 0; j < 4; ++j) hist[j][tid] = 0u;
    __syncthreads();
    for (int i0 = tid * 4; i0 < KN; i0 += 1024) {
        uint2 v = *(const uint2*)&srow[i0];
        unsigned k0 = fkey16(v.x), k1 = fkey16(v.x >> 16), k2 = fkey16(v.y), k3 = fkey16(v.y >> 16);
        if ((k0 >> 8) == selHi) atomicAdd(&hist[w][k0 & 255u], 1u);
        if ((k1 >> 8) == selHi) atomicAdd(&hist[w][k1 & 255u], 1u);
        if ((k2 >> 8) == selHi) atomicAdd(&hist[w][k2 & 255u], 1u);
        if ((k3 >> 8) == selHi) atomicAdd(&hist[w][k3 & 255u], 1u);
    }
    __syncthreads();
    if (tid == 0) {
        unsigned acc = s_cntAbove; int chosen = 0;
        for (int bin = 255; bin >= 0; --bin) {
            unsigned h = hist[0][bin] + hist[1][bin] + hist[2][bin] + hist[3][bin];
            if (acc + h >= (unsigned)knn) { chosen = bin; break; }
            acc += h;
        }
        s_cntAbove = acc; s_sel = (selHi << 8) | (unsigned)chosen;
    }
    __syncthreads();
    unsigned tu = s_sel;
    unsigned cgt = s_cntAbove;
    const float invT = 1.0f / 0.07f;
    float Zl = 0.f, Nl = 0.f;
    for (int i0 = tid * 4; i0 < KN; i0 += 1024) {
        uint2 v = *(const uint2*)&srow[i0];
        unsigned bits[4] = {v.x & 0xFFFFu, v.x >> 16, v.y & 0xFFFFu, v.y >> 16};
        #pragma unroll
        for (int j = 0; j < 4; ++j) {
            unsigned u = fkey16(bits[j]);
            if (u > tu) {
                float e = __expf(bf2f((unsigned short)bits[j]) * invT);
                Zl += e;
                if (qlabel[i0 + j] == tgt) Nl += e;
            } else if (u == tu) {
                unsigned pos = atomicAdd(&eqCount, 1u);
                if (pos < EQ_CAP) eqIdx[pos] = i0 + j;
            }
        }
    }
    redZ[tid] = Zl; redN[tid] = Nl;
    __syncthreads();
    for (int s = 128; s > 0; s >>= 1) {
        if (tid < s) { redZ[tid] += redZ[tid + s]; redN[tid] += redN[tid + s]; }
        __syncthreads();
    }
    if (tid == 0) {
        float Z = redZ[0], num = redN[0];
        int neq = (int)(eqCount < (unsigned)EQ_CAP ? eqCount : (unsigned)EQ_CAP);
        int needed = knn - (int)cgt;
        if (needed > neq) needed = neq;
        for (int a = 1; a < neq; ++a) {
            int v = eqIdx[a]; int b2 = a - 1;
            while (b2 >= 0 && eqIdx[b2] > v) { eqIdx[b2 + 1] = eqIdx[b2]; --b2; }
            eqIdx[b2 + 1] = v;
        }
        unsigned tb = (tu & 0x8000u) ? (tu & 0x7FFFu) : ((~tu) & 0xFFFFu);
        float wt = __expf(bf2f((unsigned short)tb) * invT);
        for (int a = 0; a < needed; ++a) {
            Z += wt;
            if (qlabel[eqIdx[a]] == tgt) num += wt;
        }
        float gt = num / Z;
        if (gt > 1e-8f) atomicAdd(out0, -logf(gt) * (1.0f / (float)BN));
    }
}

// ---- dc gemm v4: 2-phase double-buffered pipeline (T3-minimum recipe).
// BK=32; LDS 2x(A 8KB + B 16KB) = 48KB. Each iteration: issue next tile's
// global_load_lds FIRST, then ds_read+MFMA current tile, then one barrier.
// The barrier's vmcnt(0) drain now waits on loads whose latency was hidden
// under the compute phase + 2-3 resident blocks.
// Swizzles (src-side XOR on 16B chunks, rule #21: linear LDS dest):
//   A rows = 64B (4 chunks):  chunk ^= (row>>1)&3  -> 2 lanes/bank on read
//   B rows = 128B (8 chunks): chunk ^= row&7       -> 2 lanes/bank on read ----
__global__ void __launch_bounds__(256, 3) dc_gemm(const unsigned short* __restrict__ E,
                                                  const float* __restrict__ P,
                                                  float* __restrict__ dct) {
    __shared__ unsigned short As[2][128 * 32];   // bf16, rows of 32 (64B)
    __shared__ float Bsf[2][128 * 32];           // f32, rows of 32 (128B)
    int tid = threadIdx.x;
    int c0 = blockIdx.x * 128, m0 = blockIdx.y * 128;
    int kb = blockIdx.z * (KN / 32);             // 2048-wide K slab, 64 tiles of 32
    int lane = tid & 63, w = tid >> 6;
    int l15 = lane & 15, quad = lane >> 4;
    int wm = w & 1, wn = w >> 1;
    // A staging: rows tr, tr+64 (2 of 128), chunk chA of 4 per row
    int tr = tid >> 2, chA = tid & 3;
    int sa = (chA ^ ((tr >> 1) & 3)) << 3;       // ushort offset within 32-ushort row
    // B staging: rows i*32+br (4 of 128), chunk cb of 8 per row
    int br = tid >> 3, cb = tid & 7;
    int sb = (cb ^ (br & 7)) << 2;               // float offset within 32-float row
    f32x4 acc[4][4];
    #pragma unroll
    for (int r = 0; r < 4; ++r)
        #pragma unroll
        for (int c = 0; c < 4; ++c)
            #pragma unroll
            for (int j = 0; j < 4; ++j) acc[r][c][j] = 0.f;

    auto stage = [&](int buf, int kpos) {
        #pragma unroll
        for (int i = 0; i < 2; ++i)
            async16(E + (size_t)(m0 + i * 64 + tr) * KN + kpos + sa,
                    &As[buf][(i * 256 + tid) * 8]);
        #pragma unroll
        for (int i = 0; i < 4; ++i) {
            int gr = c0 + i * 32 + br;
            if (gr > CN - 1) gr = CN - 1;   // clamp; garbage lands in dct cols >=1000
            async16(P + (size_t)gr * KN + kpos + sb, &Bsf[buf][(i * 256 + tid) * 4]);
        }
    };

    stage(0, kb);
    __syncthreads();
    for (int t = 0; t < 64; ++t) {
        int cur = t & 1;
        if (t < 63) stage(cur ^ 1, kb + (t + 1) * 32);
        const unsigned short* Ab = As[cur];
        const float* Bb = Bsf[cur];
        bf16x8 af[4], bfr[4];
        #pragma unroll
        for (int r = 0; r < 4; ++r) {
            int arow = wm * 64 + r * 16 + l15;
            af[r] = *(const bf16x8*)&Ab[arow * 32 + ((quad ^ ((arow >> 1) & 3)) << 3)];
        }
        #pragma unroll
        for (int c = 0; c < 4; ++c) {
            int brow = wn * 64 + c * 16 + l15;
            int k7 = brow & 7;
            float4 ra = *(const float4*)&Bb[brow * 32 + (((quad * 2) ^ k7) << 2)];
            float4 rb = *(const float4*)&Bb[brow * 32 + (((quad * 2 + 1) ^ k7) << 2)];
            uint4 pk;
            pk.x = cvtpk(ra.x, ra.y); pk.y = cvtpk(ra.z, ra.w);
            pk.z = cvtpk(rb.x, rb.y); pk.w = cvtpk(rb.z, rb.w);
            bfr[c] = *(bf16x8*)&pk;
        }
        #pragma unroll
        for (int r = 0; r < 4; ++r)
            #pragma unroll
            for (int c = 0; c < 4; ++c)
                acc[r][c] = __builtin_amdgcn_mfma_f32_16x16x32_bf16(af[r], bfr[c], acc[r][c], 0, 0, 0);
        __syncthreads();
    }
    #pragma unroll
    for (int r = 0; r < 4; ++r)
        #pragma unroll
        for (int reg = 0; reg < 4; ++reg) {
            int m = m0 + wm * 64 + r * 16 + quad * 4 + reg;
            #pragma unroll
            for (int c = 0; c < 4; ++c) {
                int cc = c0 + wn * 64 + c * 16 + l15;
                atomicAdd(&dct[m * 1024 + cc], acc[r][c][reg]);
            }
        }
}

// ---- log_softmax(q_logits), qmask, fc loss ----
__global__ void __launch_bounds__(256) logq_fc(const float* __restrict__ x_all,
                                               const int* __restrict__ target,
                                               float* __restrict__ logq,
                                               float* __restrict__ qmask,
                                               float* __restrict__ out1) {
    int row = blockIdx.x, tid = threadIdx.x;
    const float* x = x_all + (size_t)row * CN;
    __shared__ float red[256], red2[256];
    float mx = -INFINITY, mn = INFINITY;
    for (int c = tid; c < CN; c += 256) { float v = x[c]; mx = fmaxf(mx, v); mn = fminf(mn, v); }
    red[tid] = mx; red2[tid] = mn;
    __syncthreads();
    for (int s = 128; s > 0; s >>= 1) {
        if (tid < s) { red[tid] = fmaxf(red[tid], red[tid + s]); red2[tid] = fminf(red2[tid], red2[tid + s]); }
        __syncthreads();
    }
    mx = red[0]; mn = red2[0];
    __syncthreads();
    float se = 0.f, sx = 0.f;
    for (int c = tid; c < CN; c += 256) { float v = x[c]; se += __expf(v - mx); sx += v; }
    red[tid] = se; red2[tid] = sx;
    __syncthreads();
    for (int s = 128; s > 0; s >>= 1) {
        if (tid < s) { red[tid] += red[tid + s]; red2[tid] += red2[tid + s]; }
        __syncthreads();
    }
    float lse = mx + logf(red[0]);
    float sumlogq = red2[0] - (float)CN * lse;
    for (int c = tid; c < CN; c += 256) logq[(size_t)row * CN + c] = x[c] - lse;
    if (tid == 0) {
        float lqt = x[target[row]] - lse;
        bool qm = (mn - lse) > logf(1e-8f);
        qmask[row] = qm ? 1.0f : 0.0f;
        if (qm) {
            float fc = -(0.1f / 999.0f * (sumlogq - lqt) + 0.9f * lqt);
            atomicAdd(out1, fc * (1.0f / (float)BN));
        }
    }
}

// ---- dc loss ----
__global__ void __launch_bounds__(256) dc_loss(const float* __restrict__ dct,
                                               const float* __restrict__ logq,
                                               const float* __restrict__ qmask,
                                               const float* __restrict__ Z,
                                               float* __restrict__ out2) {
    int row = blockIdx.x, tid = threadIdx.x;
    __shared__ float red[256];
    float invZ = 1.0f / Z[row];
    float s = 0.f;
    for (int c = tid; c < CN; c += 256) {
        float T = dct[row * 1024 + c] * invZ;
        if (T > 0.f) s += T * (logf(T) - logq[(size_t)row * CN + c]);
    }
    red[tid] = s;
    __syncthreads();
    for (int st = 128; st > 0; st >>= 1) {
        if (tid < st) red[tid] += red[tid + st];
        __syncthreads();
    }
    if (tid == 0 && qmask[row] > 0.f)
        atomicAdd(out2, red[0] * (1.0f / (float)BN));
}

extern "C" void kernel_launch(void* const* d_in, const int* in_sizes, int n_in,
                              void* d_out, int out_size, void* d_ws, size_t ws_size,
                              hipStream_t stream) {
    (void)in_sizes; (void)n_in; (void)out_size;
    const float* norm_q   = (const float*)d_in[0];
    const float* q_logits = (const float*)d_in[1];
    const float* k_feat   = (const float*)d_in[2];
    const float* queue    = (const float*)d_in[4];
    const float* qlp      = (const float*)d_in[5];
    const int*   qlabel   = (const int*)d_in[6];
    const int*   target   = (const int*)d_in[7];
    const int*   knnp     = (const int*)d_in[8];
    float* out = (float*)d_out;
    char* ws = (char*)d_ws;

    const size_t SIM_B = 67108864;     // 512*65536*2
    const size_t QT_B  = 33554432;     // 65536*256*2
    const size_t AC_B  = 524288;       // 1024*256*2
    const size_t FUSED_NEED = SIM_B * 2 + QT_B + AC_B + 2097152 + 2048 + 2048000 + 2048;
    bool fused = (ws_size >= FUSED_NEED);

    unsigned short *simBF, *Ebf, *queueT, *Acat;
    float *dct, *Zb, *logq, *qmask;
    if (fused) {
        simBF  = (unsigned short*)(ws);
        Ebf    = (unsigned short*)(ws + SIM_B);
        queueT = (unsigned short*)(ws + 2 * SIM_B);
        Acat   = (unsigned short*)(ws + 2 * SIM_B + QT_B);
        dct    = (float*)(ws + 2 * SIM_B + QT_B + AC_B);
    } else {
        simBF  = (unsigned short*)(ws);
        Ebf    = simBF;   // overlay: supcon consumes simBF before E is written
        queueT = (unsigned short*)(ws + SIM_B);
        Acat   = (unsigned short*)(ws + SIM_B + QT_B);
        dct    = (float*)(ws + SIM_B + QT_B + AC_B);
    }
    Zb    = (float*)((char*)dct + 2097152);
    logq  = (float*)((char*)Zb + 2048);
    qmask = (float*)((char*)logq + 2048000);

    hipMemsetAsync(dct, 0, 2097152 + 2048, stream);   // dct + Zb
    hipMemsetAsync(d_out, 0, 3 * sizeof(float), stream);

    cvt_bf16<<<dim3(128), 256, 0, stream>>>(norm_q, Acat);
    cvt_bf16<<<dim3(128), 256, 0, stream>>>(k_feat, Acat + (size_t)BN * DN);
    transpose_q<<<dim3(KN / 64, 4), 256, 0, stream>>>(queue, queueT);

    if (fused) {
        gemm_sim<<<dim3(KN / 128, 8), 256, 0, stream>>>(Acat, queueT, simBF, Ebf, Zb, 4);
        supcon<<<dim3(BN), 256, 0, stream>>>(simBF, qlabel, target, knnp, out + 0);
    } else {
        gemm_sim<<<dim3(KN / 128, 4), 256, 0, stream>>>(Acat, queueT, simBF, nullptr, nullptr, 4);
        supcon<<<dim3(BN), 256, 0, stream>>>(simBF, qlabel, target, knnp, out + 0);
        gemm_sim<<<dim3(KN / 128, 4), 256, 0, stream>>>(Acat + (size_t)BN * DN, queueT,
                                                        nullptr, Ebf, Zb, 0);
    }
    dc_gemm<<<dim3(8, 4, 32), 256, 0, stream>>>(Ebf, qlp, dct);
    logq_fc<<<dim3(BN), 256, 0, stream>>>(q_logits, target, logq, qmask, out + 1);
    dc_loss<<<dim3(BN), 256, 0, stream>>>(dct, logq, qmask, Zb, out + 2);
}

// Round 4
// 735.671 us; speedup vs baseline: 1.1568x; 1.1568x over previous
//
#include <hip/hip_runtime.h>
#include <math.h>

#define BN 512
#define DN 256
#define KN 65536
#define CN 1000
#define EQ_CAP 512
#define EPSTR 136   // padded epilogue LDS stride (ushorts)

typedef __attribute__((ext_vector_type(8))) short bf16x8;
typedef __attribute__((ext_vector_type(4))) float f32x4;

__device__ __forceinline__ unsigned short f2bf(float f) {
    unsigned u = __float_as_uint(f);
    unsigned r = (u + 0x7FFFu + ((u >> 16) & 1u)) >> 16;
    return (unsigned short)r;
}
__device__ __forceinline__ float bf2f(unsigned short h) {
    return __uint_as_float(((unsigned)h) << 16);
}
__device__ __forceinline__ unsigned fkey16(unsigned b) {
    b &= 0xFFFFu;
    return (b & 0x8000u) ? ((~b) & 0xFFFFu) : (b | 0x8000u);
}
__device__ __forceinline__ void async16(const void* g, void* l) {
    __builtin_amdgcn_global_load_lds(
        (const __attribute__((address_space(1))) unsigned*)g,
        (__attribute__((address_space(3))) unsigned*)l, 16, 0, 0);
}
// packed f32x2 -> bf16x2 (RNE), single instruction; lo -> D[15:0]
__device__ __forceinline__ unsigned cvtpk(float lo, float hi) {
    unsigned r;
    asm("v_cvt_pk_bf16_f32 %0, %1, %2" : "=v"(r) : "v"(lo), "v"(hi));
    return r;
}

// ---- fp32 -> bf16 convert (norm_q / k_feat into Acat halves) ----
__global__ void __launch_bounds__(256) cvt_bf16(const float* __restrict__ in,
                                                unsigned short* __restrict__ out) {
    int i = (blockIdx.x * 256 + threadIdx.x) * 4;
    float4 v = *(const float4*)&in[i];
    ushort4 o;
    o.x = f2bf(v.x); o.y = f2bf(v.y); o.z = f2bf(v.z); o.w = f2bf(v.w);
    *(ushort4*)&out[i] = o;
}

// ---- queue [256,65536] f32 -> queueT [65536,256] bf16 ----
__global__ void __launch_bounds__(256) transpose_q(const float* __restrict__ Q,
                                                   unsigned short* __restrict__ Qt) {
    __shared__ float T[64][65];
    int tid = threadIdx.x;
    int n0 = blockIdx.x * 64;
    int d0 = blockIdx.y * 64;
    #pragma unroll
    for (int i = 0; i < 4; ++i) {
        int flat = i * 256 + tid;
        int d = flat >> 4, nq = (flat & 15) * 4;
        float4 v = *(const float4*)&Q[(size_t)(d0 + d) * KN + n0 + nq];
        T[d][nq] = v.x; T[d][nq + 1] = v.y; T[d][nq + 2] = v.z; T[d][nq + 3] = v.w;
    }
    __syncthreads();
    int n = tid >> 2, dbase = (tid & 3) * 16;
    unsigned u[8];
    #pragma unroll
    for (int j = 0; j < 8; ++j) {
        unsigned short a = f2bf(T[dbase + 2 * j][n]);
        unsigned short b = f2bf(T[dbase + 2 * j + 1][n]);
        u[j] = (unsigned)a | ((unsigned)b << 16);
    }
    unsigned short* o = &Qt[(size_t)(n0 + n) * DN + d0 + dbase];
    *(uint4*)o = make_uint4(u[0], u[1], u[2], u[3]);
    *(uint4*)(o + 8) = make_uint4(u[4], u[5], u[6], u[7]);
}

// ---- MFMA GEMM, swapped operands, LDS-transposed coalesced epilogue.
// Blocks with blockIdx.y >= mBlockSplit apply exp(10x) and accumulate row sums.
__global__ void __launch_bounds__(256) gemm_sim(const unsigned short* __restrict__ A,
                                                const unsigned short* __restrict__ Bt,
                                                unsigned short* __restrict__ simOut,
                                                unsigned short* __restrict__ expOut,
                                                float* __restrict__ Zb,
                                                int mBlockSplit) {
    __shared__ unsigned short smem[128 * 64 * 2];   // As | Bs, reused as epilogue buf
    __shared__ float Zred[128];
    unsigned short* As = smem;
    unsigned short* Bs = smem + 128 * 64;
    int tid = threadIdx.x;
    int n0 = blockIdx.x * 128, m0 = blockIdx.y * 128;
    bool isExp = ((int)blockIdx.y >= mBlockSplit);
    int lane = tid & 63, w = tid >> 6;
    int l15 = lane & 15, quad = lane >> 4;
    int wm = w & 1, wn = w >> 1;
    f32x4 acc[4][4];   // [mi][ni]; D layout: col(l15)=m, row(quad*4+reg)=n
    #pragma unroll
    for (int mi = 0; mi < 4; ++mi)
        #pragma unroll
        for (int ni = 0; ni < 4; ++ni)
            #pragma unroll
            for (int j = 0; j < 4; ++j) acc[mi][ni][j] = 0.f;

    for (int k0 = 0; k0 < DN; k0 += 64) {
        #pragma unroll
        for (int i = 0; i < 4; ++i) {
            int f = (i * 256 + tid) * 8;
            async16(A + (size_t)(m0 + (f >> 6)) * DN + k0 + (f & 63), &As[f]);
        }
        #pragma unroll
        for (int i = 0; i < 4; ++i) {
            int f = (i * 256 + tid) * 8;
            async16(Bt + (size_t)(n0 + (f >> 6)) * DN + k0 + (f & 63), &Bs[f]);
        }
        __syncthreads();
        #pragma unroll
        for (int ks = 0; ks < 2; ++ks) {
            bf16x8 am[4], bn[4];
            #pragma unroll
            for (int mi = 0; mi < 4; ++mi)
                am[mi] = *(const bf16x8*)&As[(wm * 64 + mi * 16 + l15) * 64 + ks * 32 + quad * 8];
            #pragma unroll
            for (int ni = 0; ni < 4; ++ni)
                bn[ni] = *(const bf16x8*)&Bs[(wn * 64 + ni * 16 + l15) * 64 + ks * 32 + quad * 8];
            #pragma unroll
            for (int mi = 0; mi < 4; ++mi)
                #pragma unroll
                for (int ni = 0; ni < 4; ++ni)
                    acc[mi][ni] = __builtin_amdgcn_mfma_f32_16x16x32_bf16(bn[ni], am[mi], acc[mi][ni], 0, 0, 0);
        }
        __syncthreads();
    }

    unsigned short* obase = isExp ? expOut : simOut;
    int orow0 = isExp ? (m0 - mBlockSplit * 128) : m0;
    float rsum[4] = {0.f, 0.f, 0.f, 0.f};

    // two rounds of 64 rows each through padded LDS, then coalesced 16B stores
    #pragma unroll
    for (int round = 0; round < 2; ++round) {
        if (wm == round) {
            #pragma unroll
            for (int mi = 0; mi < 4; ++mi) {
                int mrow = mi * 16 + l15;   // within round
                #pragma unroll
                for (int ni = 0; ni < 4; ++ni) {
                    int nc = wn * 64 + ni * 16 + quad * 4;
                    float v0 = acc[mi][ni][0], v1 = acc[mi][ni][1];
                    float v2 = acc[mi][ni][2], v3 = acc[mi][ni][3];
                    if (isExp) {
                        v0 = __expf(v0 * 10.0f); v1 = __expf(v1 * 10.0f);
                        v2 = __expf(v2 * 10.0f); v3 = __expf(v3 * 10.0f);
                    }
                    unsigned short u0 = f2bf(v0), u1 = f2bf(v1), u2 = f2bf(v2), u3 = f2bf(v3);
                    if (isExp) rsum[mi] += bf2f(u0) + bf2f(u1) + bf2f(u2) + bf2f(u3);
                    *(uint2*)&smem[mrow * EPSTR + nc] =
                        make_uint2((unsigned)u0 | ((unsigned)u1 << 16),
                                   (unsigned)u2 | ((unsigned)u3 << 16));
                }
            }
        }
        __syncthreads();
        #pragma unroll
        for (int j = 0; j < 4; ++j) {
            int fc = j * 256 + tid;          // 0..1023
            int mr = fc >> 4;                // 0..63
            int ch = fc & 15;                // 16-byte chunk within row
            uint4 val = *(uint4*)&smem[mr * EPSTR + ch * 8];
            int g = orow0 + round * 64 + mr;
            *(uint4*)&obase[(size_t)g * KN + n0 + ch * 8] = val;
        }
        __syncthreads();
    }

    if (isExp) {
        float v4[4];
        #pragma unroll
        for (int mi = 0; mi < 4; ++mi) {
            float v = rsum[mi];
            v += __shfl_xor(v, 16, 64);
            v += __shfl_xor(v, 32, 64);
            v4[mi] = v;
        }
        if (wn == 0 && quad == 0) {
            #pragma unroll
            for (int mi = 0; mi < 4; ++mi) Zred[wm * 64 + mi * 16 + l15] = v4[mi];
        }
        __syncthreads();
        if (wn == 1 && quad == 0) {
            #pragma unroll
            for (int mi = 0; mi < 4; ++mi) Zred[wm * 64 + mi * 16 + l15] += v4[mi];
        }
        __syncthreads();
        if (tid < 128) atomicAdd(&Zb[orow0 + tid], Zred[tid]);
    }
}

// ---- supcon on bf16 sim: 2-pass radix select over 16-bit keys + fused loss ----
__global__ void __launch_bounds__(256) supcon(const unsigned short* __restrict__ sim,
                                              const int* __restrict__ qlabel,
                                              const int* __restrict__ target,
                                              const int* __restrict__ knnp,
                                              float* __restrict__ out0) {
    __shared__ unsigned hist[4][256];
    __shared__ unsigned s_sel, s_cntAbove;
    __shared__ int eqIdx[EQ_CAP];
    __shared__ unsigned eqCount;
    __shared__ float redZ[256], redN[256];
    int tid = threadIdx.x, w = tid >> 6;
    int row = blockIdx.x;
    const unsigned short* srow = sim + (size_t)row * KN;
    int knn = *knnp;
    int tgt = target[row];
    if (tid == 0) { eqCount = 0u; }
    #pragma unroll
    for (int j = 0; j < 4; ++j) hist[j][tid] = 0u;
    __syncthreads();
    for (int i0 = tid * 4; i0 < KN; i0 += 1024) {
        uint2 v = *(const uint2*)&srow[i0];
        atomicAdd(&hist[w][fkey16(v.x) >> 8], 1u);
        atomicAdd(&hist[w][fkey16(v.x >> 16) >> 8], 1u);
        atomicAdd(&hist[w][fkey16(v.y) >> 8], 1u);
        atomicAdd(&hist[w][fkey16(v.y >> 16) >> 8], 1u);
    }
    __syncthreads();
    if (tid == 0) {
        unsigned acc = 0; int chosen = 0;
        for (int bin = 255; bin >= 0; --bin) {
            unsigned h = hist[0][bin] + hist[1][bin] + hist[2][bin] + hist[3][bin];
            if (acc + h >= (unsigned)knn) { chosen = bin; break; }
            acc += h;
        }
        s_cntAbove = acc; s_sel = (unsigned)chosen;
    }
    __syncthreads();
    unsigned selHi = s_sel;
    #pragma unroll
    for (int j = 0; j < 4; ++j) hist[j][tid] = 0u;
    __syncthreads();
    for (int i0 = tid * 4; i0 < KN; i0 += 1024) {
        uint2 v = *(const uint2*)&srow[i0];
        unsigned k0 = fkey16(v.x), k1 = fkey16(v.x >> 16), k2 = fkey16(v.y), k3 = fkey16(v.y >> 16);
        if ((k0 >> 8) == selHi) atomicAdd(&hist[w][k0 & 255u], 1u);
        if ((k1 >> 8) == selHi) atomicAdd(&hist[w][k1 & 255u], 1u);
        if ((k2 >> 8) == selHi) atomicAdd(&hist[w][k2 & 255u], 1u);
        if ((k3 >> 8) == selHi) atomicAdd(&hist[w][k3 & 255u], 1u);
    }
    __syncthreads();
    if (tid == 0) {
        unsigned acc = s_cntAbove; int chosen = 0;
        for (int bin = 255; bin >= 0; --bin) {
            unsigned h = hist[0][bin] + hist[1][bin] + hist[2][bin] + hist[3][bin];
            if (acc + h >= (unsigned)knn) { chosen = bin; break; }
            acc += h;
        }
        s_cntAbove = acc; s_sel = (selHi << 8) | (unsigned)chosen;
    }
    __syncthreads();
    unsigned tu = s_sel;
    unsigned cgt = s_cntAbove;
    const float invT = 1.0f / 0.07f;
    float Zl = 0.f, Nl = 0.f;
    for (int i0 = tid * 4; i0 < KN; i0 += 1024) {
        uint2 v = *(const uint2*)&srow[i0];
        unsigned bits[4] = {v.x & 0xFFFFu, v.x >> 16, v.y & 0xFFFFu, v.y >> 16};
        #pragma unroll
        for (int j = 0; j < 4; ++j) {
            unsigned u = fkey16(bits[j]);
            if (u > tu) {
                float e = __expf(bf2f((unsigned short)bits[j]) * invT);
                Zl += e;
                if (qlabel[i0 + j] == tgt) Nl += e;
            } else if (u == tu) {
                unsigned pos = atomicAdd(&eqCount, 1u);
                if (pos < EQ_CAP) eqIdx[pos] = i0 + j;
            }
        }
    }
    redZ[tid] = Zl; redN[tid] = Nl;
    __syncthreads();
    for (int s = 128; s > 0; s >>= 1) {
        if (tid < s) { redZ[tid] += redZ[tid + s]; redN[tid] += redN[tid + s]; }
        __syncthreads();
    }
    if (tid == 0) {
        float Z = redZ[0], num = redN[0];
        int neq = (int)(eqCount < (unsigned)EQ_CAP ? eqCount : (unsigned)EQ_CAP);
        int needed = knn - (int)cgt;
        if (needed > neq) needed = neq;
        for (int a = 1; a < neq; ++a) {
            int v = eqIdx[a]; int b2 = a - 1;
            while (b2 >= 0 && eqIdx[b2] > v) { eqIdx[b2 + 1] = eqIdx[b2]; --b2; }
            eqIdx[b2 + 1] = v;
        }
        unsigned tb = (tu & 0x8000u) ? (tu & 0x7FFFu) : ((~tu) & 0xFFFFu);
        float wt = __expf(bf2f((unsigned short)tb) * invT);
        for (int a = 0; a < needed; ++a) {
            Z += wt;
            if (qlabel[eqIdx[a]] == tgt) num += wt;
        }
        float gt = num / Z;
        if (gt > 1e-8f) atomicAdd(out0, -logf(gt) * (1.0f / (float)BN));
    }
}

// ---- dc gemm v5: round-2 (v3) inner structure, BM=256 (two A-tiles share
// one staged B-tile). Per-CU drains halve (2 blocks x 32 iters vs 4 x 32),
// B-traffic per FLOP halves, intensity 22->33 FLOP/LDS-byte.
// LDS = A 32KB bf16 + B 32KB f32 = 64KB -> 2 blocks/CU; grid 512 = exactly
// 2/CU, one scheduling round. Staging/read swizzles identical to v3. ----
__global__ void __launch_bounds__(256, 2) dc_gemm(const unsigned short* __restrict__ E,
                                                  const float* __restrict__ P,
                                                  float* __restrict__ dct) {
    __shared__ unsigned short As[256 * 64];   // bf16, 256 m-rows of 64 (128B)
    __shared__ float Bsf[128 * 64];           // f32, 128 c-rows of 64 (256B)
    int tid = threadIdx.x;
    int c0 = blockIdx.x * 128, m0 = blockIdx.y * 256;
    int kb = blockIdx.z * (KN / 32);          // 2048-wide K slab
    int lane = tid & 63, w = tid >> 6;
    int l15 = lane & 15, quad = lane >> 4;
    int wm = w & 1, wn = w >> 1;
    // A staging: rows i*32+tr (8 of 256), 16B chunk chA of 8 per row
    int tr = tid >> 3, chA = tid & 7;
    int sa = (chA ^ (tr & 7)) << 3;           // ushort offset within row (swizzled src)
    // B staging: rows i*16+br (8 of 128), 16B chunk cb of 16 per row
    int br = tid >> 4, cbB = tid & 15;
    int sb = (cbB ^ (br & 7)) << 2;           // f32 offset within row (swizzled src)
    const int swr = l15 & 7;                  // read-side swizzle (row&7 == l15&7)
    f32x4 acc[2][4][4];
    #pragma unroll
    for (int mt = 0; mt < 2; ++mt)
        #pragma unroll
        for (int r = 0; r < 4; ++r)
            #pragma unroll
            for (int c = 0; c < 4; ++c)
                #pragma unroll
                for (int j = 0; j < 4; ++j) acc[mt][r][c][j] = 0.f;

    for (int kc = 0; kc < KN / 32; kc += 64) {
        // A tiles: 256x64 bf16, direct-to-LDS, pre-swizzled global source
        #pragma unroll
        for (int i = 0; i < 8; ++i) {
            int row = i * 32 + tr;
            async16(E + (size_t)(m0 + row) * KN + kb + kc + sa, &As[(i * 256 + tid) * 8]);
        }
        // B tile: 128x64 f32, direct-to-LDS, pre-swizzled global source.
        // Rows past CN-1 clamp to row CN-1; garbage lands in dct cols >=1000 (never read).
        #pragma unroll
        for (int i = 0; i < 8; ++i) {
            int gr = c0 + i * 16 + br;
            if (gr > CN - 1) gr = CN - 1;
            async16(P + (size_t)gr * KN + kb + kc + sb, &Bsf[(i * 256 + tid) * 4]);
        }
        __syncthreads();
        #pragma unroll
        for (int ks = 0; ks < 2; ++ks) {
            bf16x8 af[2][4], bfr[4];
            #pragma unroll
            for (int mt = 0; mt < 2; ++mt)
                #pragma unroll
                for (int r = 0; r < 4; ++r) {
                    int arow = mt * 128 + wm * 64 + r * 16 + l15;
                    af[mt][r] = *(const bf16x8*)&As[arow * 64 + (((ks * 4 + quad) ^ swr) << 3)];
                }
            #pragma unroll
            for (int c = 0; c < 4; ++c) {
                int brow = wn * 64 + c * 16 + l15;
                int ck = ks * 8 + quad * 2;
                float4 ra = *(const float4*)&Bsf[brow * 64 + ((ck ^ swr) << 2)];
                float4 rb = *(const float4*)&Bsf[brow * 64 + (((ck + 1) ^ swr) << 2)];
                uint4 pk;
                pk.x = cvtpk(ra.x, ra.y); pk.y = cvtpk(ra.z, ra.w);
                pk.z = cvtpk(rb.x, rb.y); pk.w = cvtpk(rb.z, rb.w);
                bfr[c] = *(bf16x8*)&pk;
            }
            #pragma unroll
            for (int mt = 0; mt < 2; ++mt)
                #pragma unroll
                for (int r = 0; r < 4; ++r)
                    #pragma unroll
                    for (int c = 0; c < 4; ++c)
                        acc[mt][r][c] = __builtin_amdgcn_mfma_f32_16x16x32_bf16(
                            af[mt][r], bfr[c], acc[mt][r][c], 0, 0, 0);
        }
        __syncthreads();
    }
    #pragma unroll
    for (int mt = 0; mt < 2; ++mt)
        #pragma unroll
        for (int r = 0; r < 4; ++r)
            #pragma unroll
            for (int reg = 0; reg < 4; ++reg) {
                int m = m0 + mt * 128 + wm * 64 + r * 16 + quad * 4 + reg;
                #pragma unroll
                for (int c = 0; c < 4; ++c) {
                    int cc = c0 + wn * 64 + c * 16 + l15;
                    atomicAdd(&dct[m * 1024 + cc], acc[mt][r][c][reg]);
                }
            }
}

// ---- log_softmax(q_logits), qmask, fc loss ----
__global__ void __launch_bounds__(256) logq_fc(const float* __restrict__ x_all,
                                               const int* __restrict__ target,
                                               float* __restrict__ logq,
                                               float* __restrict__ qmask,
                                               float* __restrict__ out1) {
    int row = blockIdx.x, tid = threadIdx.x;
    const float* x = x_all + (size_t)row * CN;
    __shared__ float red[256], red2[256];
    float mx = -INFINITY, mn = INFINITY;
    for (int c = tid; c < CN; c += 256) { float v = x[c]; mx = fmaxf(mx, v); mn = fminf(mn, v); }
    red[tid] = mx; red2[tid] = mn;
    __syncthreads();
    for (int s = 128; s > 0; s >>= 1) {
        if (tid < s) { red[tid] = fmaxf(red[tid], red[tid + s]); red2[tid] = fminf(red2[tid], red2[tid + s]); }
        __syncthreads();
    }
    mx = red[0]; mn = red2[0];
    __syncthreads();
    float se = 0.f, sx = 0.f;
    for (int c = tid; c < CN; c += 256) { float v = x[c]; se += __expf(v - mx); sx += v; }
    red[tid] = se; red2[tid] = sx;
    __syncthreads();
    for (int s = 128; s > 0; s >>= 1) {
        if (tid < s) { red[tid] += red[tid + s]; red2[tid] += red2[tid + s]; }
        __syncthreads();
    }
    float lse = mx + logf(red[0]);
    float sumlogq = red2[0] - (float)CN * lse;
    for (int c = tid; c < CN; c += 256) logq[(size_t)row * CN + c] = x[c] - lse;
    if (tid == 0) {
        float lqt = x[target[row]] - lse;
        bool qm = (mn - lse) > logf(1e-8f);
        qmask[row] = qm ? 1.0f : 0.0f;
        if (qm) {
            float fc = -(0.1f / 999.0f * (sumlogq - lqt) + 0.9f * lqt);
            atomicAdd(out1, fc * (1.0f / (float)BN));
        }
    }
}

// ---- dc loss ----
__global__ void __launch_bounds__(256) dc_loss(const float* __restrict__ dct,
                                               const float* __restrict__ logq,
                                               const float* __restrict__ qmask,
                                               const float* __restrict__ Z,
                                               float* __restrict__ out2) {
    int row = blockIdx.x, tid = threadIdx.x;
    __shared__ float red[256];
    float invZ = 1.0f / Z[row];
    float s = 0.f;
    for (int c = tid; c < CN; c += 256) {
        float T = dct[row * 1024 + c] * invZ;
        if (T > 0.f) s += T * (logf(T) - logq[(size_t)row * CN + c]);
    }
    red[tid] = s;
    __syncthreads();
    for (int st = 128; st > 0; st >>= 1) {
        if (tid < st) red[tid] += red[tid + st];
        __syncthreads();
    }
    if (tid == 0 && qmask[row] > 0.f)
        atomicAdd(out2, red[0] * (1.0f / (float)BN));
}

extern "C" void kernel_launch(void* const* d_in, const int* in_sizes, int n_in,
                              void* d_out, int out_size, void* d_ws, size_t ws_size,
                              hipStream_t stream) {
    (void)in_sizes; (void)n_in; (void)out_size;
    const float* norm_q   = (const float*)d_in[0];
    const float* q_logits = (const float*)d_in[1];
    const float* k_feat   = (const float*)d_in[2];
    const float* queue    = (const float*)d_in[4];
    const float* qlp      = (const float*)d_in[5];
    const int*   qlabel   = (const int*)d_in[6];
    const int*   target   = (const int*)d_in[7];
    const int*   knnp     = (const int*)d_in[8];
    float* out = (float*)d_out;
    char* ws = (char*)d_ws;

    const size_t SIM_B = 67108864;     // 512*65536*2
    const size_t QT_B  = 33554432;     // 65536*256*2
    const size_t AC_B  = 524288;       // 1024*256*2
    const size_t FUSED_NEED = SIM_B * 2 + QT_B + AC_B + 2097152 + 2048 + 2048000 + 2048;
    bool fused = (ws_size >= FUSED_NEED);

    unsigned short *simBF, *Ebf, *queueT, *Acat;
    float *dct, *Zb, *logq, *qmask;
    if (fused) {
        simBF  = (unsigned short*)(ws);
        Ebf    = (unsigned short*)(ws + SIM_B);
        queueT = (unsigned short*)(ws + 2 * SIM_B);
        Acat   = (unsigned short*)(ws + 2 * SIM_B + QT_B);
        dct    = (float*)(ws + 2 * SIM_B + QT_B + AC_B);
    } else {
        simBF  = (unsigned short*)(ws);
        Ebf    = simBF;   // overlay: supcon consumes simBF before E is written
        queueT = (unsigned short*)(ws + SIM_B);
        Acat   = (unsigned short*)(ws + SIM_B + QT_B);
        dct    = (float*)(ws + SIM_B + QT_B + AC_B);
    }
    Zb    = (float*)((char*)dct + 2097152);
    logq  = (float*)((char*)Zb + 2048);
    qmask = (float*)((char*)logq + 2048000);

    hipMemsetAsync(dct, 0, 2097152 + 2048, stream);   // dct + Zb
    hipMemsetAsync(d_out, 0, 3 * sizeof(float), stream);

    cvt_bf16<<<dim3(128), 256, 0, stream>>>(norm_q, Acat);
    cvt_bf16<<<dim3(128), 256, 0, stream>>>(k_feat, Acat + (size_t)BN * DN);
    transpose_q<<<dim3(KN / 64, 4), 256, 0, stream>>>(queue, queueT);

    if (fused) {
        gemm_sim<<<dim3(KN / 128, 8), 256, 0, stream>>>(Acat, queueT, simBF, Ebf, Zb, 4);
        supcon<<<dim3(BN), 256, 0, stream>>>(simBF, qlabel, target, knnp, out + 0);
    } else {
        gemm_sim<<<dim3(KN / 128, 4), 256, 0, stream>>>(Acat, queueT, simBF, nullptr, nullptr, 4);
        supcon<<<dim3(BN), 256, 0, stream>>>(simBF, qlabel, target, knnp, out + 0);
        gemm_sim<<<dim3(KN / 128, 4), 256, 0, stream>>>(Acat + (size_t)BN * DN, queueT,
                                                        nullptr, Ebf, Zb, 0);
    }
    dc_gemm<<<dim3(8, 2, 32), 256, 0, stream>>>(Ebf, qlp, dct);
    logq_fc<<<dim3(BN), 256, 0, stream>>>(q_logits, target, logq, qmask, out + 1);
    dc_loss<<<dim3(BN), 256, 0, stream>>>(dct, logq, qmask, Zb, out + 2);
}

// Round 7
// 725.696 us; speedup vs baseline: 1.1727x; 1.0137x over previous
//
#include <hip/hip_runtime.h>
#include <math.h>

#define BN 512
#define DN 256
#define KN 65536
#define CN 1000
#define EQ_CAP 512
#define EPSTR 136   // padded epilogue LDS stride (ushorts)

typedef __attribute__((ext_vector_type(8))) short bf16x8;
typedef __attribute__((ext_vector_type(4))) float f32x4;

__device__ __forceinline__ unsigned short f2bf(float f) {
    unsigned u = __float_as_uint(f);
    unsigned r = (u + 0x7FFFu + ((u >> 16) & 1u)) >> 16;
    return (unsigned short)r;
}
__device__ __forceinline__ float bf2f(unsigned short h) {
    return __uint_as_float(((unsigned)h) << 16);
}
__device__ __forceinline__ unsigned fkey16(unsigned b) {
    b &= 0xFFFFu;
    return (b & 0x8000u) ? ((~b) & 0xFFFFu) : (b | 0x8000u);
}
__device__ __forceinline__ void async16(const void* g, void* l) {
    __builtin_amdgcn_global_load_lds(
        (const __attribute__((address_space(1))) unsigned*)g,
        (__attribute__((address_space(3))) unsigned*)l, 16, 0, 0);
}
// packed f32x2 -> bf16x2 (RNE), single instruction; lo -> D[15:0]
__device__ __forceinline__ unsigned cvtpk(float lo, float hi) {
    unsigned r;
    asm("v_cvt_pk_bf16_f32 %0, %1, %2" : "=v"(r) : "v"(lo), "v"(hi));
    return r;
}

// ---- fp32 -> bf16 convert (norm_q / k_feat into Acat halves) ----
__global__ void __launch_bounds__(256) cvt_bf16(const float* __restrict__ in,
                                                unsigned short* __restrict__ out) {
    int i = (blockIdx.x * 256 + threadIdx.x) * 4;
    float4 v = *(const float4*)&in[i];
    ushort4 o;
    o.x = f2bf(v.x); o.y = f2bf(v.y); o.z = f2bf(v.z); o.w = f2bf(v.w);
    *(ushort4*)&out[i] = o;
}

// ---- queue [256,65536] f32 -> queueT [65536,256] bf16 ----
__global__ void __launch_bounds__(256) transpose_q(const float* __restrict__ Q,
                                                   unsigned short* __restrict__ Qt) {
    __shared__ float T[64][65];
    int tid = threadIdx.x;
    int n0 = blockIdx.x * 64;
    int d0 = blockIdx.y * 64;
    #pragma unroll
    for (int i = 0; i < 4; ++i) {
        int flat = i * 256 + tid;
        int d = flat >> 4, nq = (flat & 15) * 4;
        float4 v = *(const float4*)&Q[(size_t)(d0 + d) * KN + n0 + nq];
        T[d][nq] = v.x; T[d][nq + 1] = v.y; T[d][nq + 2] = v.z; T[d][nq + 3] = v.w;
    }
    __syncthreads();
    int n = tid >> 2, dbase = (tid & 3) * 16;
    unsigned u[8];
    #pragma unroll
    for (int j = 0; j < 8; ++j) {
        unsigned short a = f2bf(T[dbase + 2 * j][n]);
        unsigned short b = f2bf(T[dbase + 2 * j + 1][n]);
        u[j] = (unsigned)a | ((unsigned)b << 16);
    }
    unsigned short* o = &Qt[(size_t)(n0 + n) * DN + d0 + dbase];
    *(uint4*)o = make_uint4(u[0], u[1], u[2], u[3]);
    *(uint4*)(o + 8) = make_uint4(u[4], u[5], u[6], u[7]);
}

// ---- MFMA GEMM, swapped operands, LDS-transposed coalesced epilogue.
// Blocks with blockIdx.y >= mBlockSplit apply exp(10x) and accumulate row sums.
__global__ void __launch_bounds__(256) gemm_sim(const unsigned short* __restrict__ A,
                                                const unsigned short* __restrict__ Bt,
                                                unsigned short* __restrict__ simOut,
                                                unsigned short* __restrict__ expOut,
                                                float* __restrict__ Zb,
                                                int mBlockSplit) {
    __shared__ unsigned short smem[128 * 64 * 2];   // As | Bs, reused as epilogue buf
    __shared__ float Zred[128];
    unsigned short* As = smem;
    unsigned short* Bs = smem + 128 * 64;
    int tid = threadIdx.x;
    int n0 = blockIdx.x * 128, m0 = blockIdx.y * 128;
    bool isExp = ((int)blockIdx.y >= mBlockSplit);
    int lane = tid & 63, w = tid >> 6;
    int l15 = lane & 15, quad = lane >> 4;
    int wm = w & 1, wn = w >> 1;
    f32x4 acc[4][4];   // [mi][ni]; D layout: col(l15)=m, row(quad*4+reg)=n
    #pragma unroll
    for (int mi = 0; mi < 4; ++mi)
        #pragma unroll
        for (int ni = 0; ni < 4; ++ni)
            #pragma unroll
            for (int j = 0; j < 4; ++j) acc[mi][ni][j] = 0.f;

    for (int k0 = 0; k0 < DN; k0 += 64) {
        #pragma unroll
        for (int i = 0; i < 4; ++i) {
            int f = (i * 256 + tid) * 8;
            async16(A + (size_t)(m0 + (f >> 6)) * DN + k0 + (f & 63), &As[f]);
        }
        #pragma unroll
        for (int i = 0; i < 4; ++i) {
            int f = (i * 256 + tid) * 8;
            async16(Bt + (size_t)(n0 + (f >> 6)) * DN + k0 + (f & 63), &Bs[f]);
        }
        __syncthreads();
        #pragma unroll
        for (int ks = 0; ks < 2; ++ks) {
            bf16x8 am[4], bn[4];
            #pragma unroll
            for (int mi = 0; mi < 4; ++mi)
                am[mi] = *(const bf16x8*)&As[(wm * 64 + mi * 16 + l15) * 64 + ks * 32 + quad * 8];
            #pragma unroll
            for (int ni = 0; ni < 4; ++ni)
                bn[ni] = *(const bf16x8*)&Bs[(wn * 64 + ni * 16 + l15) * 64 + ks * 32 + quad * 8];
            #pragma unroll
            for (int mi = 0; mi < 4; ++mi)
                #pragma unroll
                for (int ni = 0; ni < 4; ++ni)
                    acc[mi][ni] = __builtin_amdgcn_mfma_f32_16x16x32_bf16(bn[ni], am[mi], acc[mi][ni], 0, 0, 0);
        }
        __syncthreads();
    }

    unsigned short* obase = isExp ? expOut : simOut;
    int orow0 = isExp ? (m0 - mBlockSplit * 128) : m0;
    float rsum[4] = {0.f, 0.f, 0.f, 0.f};

    // two rounds of 64 rows each through padded LDS, then coalesced 16B stores
    #pragma unroll
    for (int round = 0; round < 2; ++round) {
        if (wm == round) {
            #pragma unroll
            for (int mi = 0; mi < 4; ++mi) {
                int mrow = mi * 16 + l15;   // within round
                #pragma unroll
                for (int ni = 0; ni < 4; ++ni) {
                    int nc = wn * 64 + ni * 16 + quad * 4;
                    float v0 = acc[mi][ni][0], v1 = acc[mi][ni][1];
                    float v2 = acc[mi][ni][2], v3 = acc[mi][ni][3];
                    if (isExp) {
                        v0 = __expf(v0 * 10.0f); v1 = __expf(v1 * 10.0f);
                        v2 = __expf(v2 * 10.0f); v3 = __expf(v3 * 10.0f);
                    }
                    unsigned short u0 = f2bf(v0), u1 = f2bf(v1), u2 = f2bf(v2), u3 = f2bf(v3);
                    if (isExp) rsum[mi] += bf2f(u0) + bf2f(u1) + bf2f(u2) + bf2f(u3);
                    *(uint2*)&smem[mrow * EPSTR + nc] =
                        make_uint2((unsigned)u0 | ((unsigned)u1 << 16),
                                   (unsigned)u2 | ((unsigned)u3 << 16));
                }
            }
        }
        __syncthreads();
        #pragma unroll
        for (int j = 0; j < 4; ++j) {
            int fc = j * 256 + tid;          // 0..1023
            int mr = fc >> 4;                // 0..63
            int ch = fc & 15;                // 16-byte chunk within row
            uint4 val = *(uint4*)&smem[mr * EPSTR + ch * 8];
            int g = orow0 + round * 64 + mr;
            *(uint4*)&obase[(size_t)g * KN + n0 + ch * 8] = val;
        }
        __syncthreads();
    }

    if (isExp) {
        float v4[4];
        #pragma unroll
        for (int mi = 0; mi < 4; ++mi) {
            float v = rsum[mi];
            v += __shfl_xor(v, 16, 64);
            v += __shfl_xor(v, 32, 64);
            v4[mi] = v;
        }
        if (wn == 0 && quad == 0) {
            #pragma unroll
            for (int mi = 0; mi < 4; ++mi) Zred[wm * 64 + mi * 16 + l15] = v4[mi];
        }
        __syncthreads();
        if (wn == 1 && quad == 0) {
            #pragma unroll
            for (int mi = 0; mi < 4; ++mi) Zred[wm * 64 + mi * 16 + l15] += v4[mi];
        }
        __syncthreads();
        if (tid < 128) atomicAdd(&Zb[orow0 + tid], Zred[tid]);
    }
}

// ---- supcon on bf16 sim: 2-pass radix select over 16-bit keys + fused loss ----
__global__ void __launch_bounds__(256) supcon(const unsigned short* __restrict__ sim,
                                              const int* __restrict__ qlabel,
                                              const int* __restrict__ target,
                                              const int* __restrict__ knnp,
                                              float* __restrict__ out0) {
    __shared__ unsigned hist[4][256];
    __shared__ unsigned s_sel, s_cntAbove;
    __shared__ int eqIdx[EQ_CAP];
    __shared__ unsigned eqCount;
    __shared__ float redZ[256], redN[256];
    int tid = threadIdx.x, w = tid >> 6;
    int row = blockIdx.x;
    const unsigned short* srow = sim + (size_t)row * KN;
    int knn = *knnp;
    int tgt = target[row];
    if (tid == 0) { eqCount = 0u; }
    #pragma unroll
    for (int j = 0; j < 4; ++j) hist[j][tid] = 0u;
    __syncthreads();
    for (int i0 = tid * 4; i0 < KN; i0 += 1024) {
        uint2 v = *(const uint2*)&srow[i0];
        atomicAdd(&hist[w][fkey16(v.x) >> 8], 1u);
        atomicAdd(&hist[w][fkey16(v.x >> 16) >> 8], 1u);
        atomicAdd(&hist[w][fkey16(v.y) >> 8], 1u);
        atomicAdd(&hist[w][fkey16(v.y >> 16) >> 8], 1u);
    }
    __syncthreads();
    if (tid == 0) {
        unsigned acc = 0; int chosen = 0;
        for (int bin = 255; bin >= 0; --bin) {
            unsigned h = hist[0][bin] + hist[1][bin] + hist[2][bin] + hist[3][bin];
            if (acc + h >= (unsigned)knn) { chosen = bin; break; }
            acc += h;
        }
        s_cntAbove = acc; s_sel = (unsigned)chosen;
    }
    __syncthreads();
    unsigned selHi = s_sel;
    #pragma unroll
    for (int j = 0; j < 4; ++j) hist[j][tid] = 0u;
    __syncthreads();
    for (int i0 = tid * 4; i0 < KN; i0 += 1024) {
        uint2 v = *(const uint2*)&srow[i0];
        unsigned k0 = fkey16(v.x), k1 = fkey16(v.x >> 16), k2 = fkey16(v.y), k3 = fkey16(v.y >> 16);
        if ((k0 >> 8) == selHi) atomicAdd(&hist[w][k0 & 255u], 1u);
        if ((k1 >> 8) == selHi) atomicAdd(&hist[w][k1 & 255u], 1u);
        if ((k2 >> 8) == selHi) atomicAdd(&hist[w][k2 & 255u], 1u);
        if ((k3 >> 8) == selHi) atomicAdd(&hist[w][k3 & 255u], 1u);
    }
    __syncthreads();
    if (tid == 0) {
        unsigned acc = s_cntAbove; int chosen = 0;
        for (int bin = 255; bin >= 0; --bin) {
            unsigned h = hist[0][bin] + hist[1][bin] + hist[2][bin] + hist[3][bin];
            if (acc + h >= (unsigned)knn) { chosen = bin; break; }
            acc += h;
        }
        s_cntAbove = acc; s_sel = (selHi << 8) | (unsigned)chosen;
    }
    __syncthreads();
    unsigned tu = s_sel;
    unsigned cgt = s_cntAbove;
    const float invT = 1.0f / 0.07f;
    float Zl = 0.f, Nl = 0.f;
    for (int i0 = tid * 4; i0 < KN; i0 += 1024) {
        uint2 v = *(const uint2*)&srow[i0];
        unsigned bits[4] = {v.x & 0xFFFFu, v.x >> 16, v.y & 0xFFFFu, v.y >> 16};
        #pragma unroll
        for (int j = 0; j < 4; ++j) {
            unsigned u = fkey16(bits[j]);
            if (u > tu) {
                float e = __expf(bf2f((unsigned short)bits[j]) * invT);
                Zl += e;
                if (qlabel[i0 + j] == tgt) Nl += e;
            } else if (u == tu) {
                unsigned pos = atomicAdd(&eqCount, 1u);
                if (pos < EQ_CAP) eqIdx[pos] = i0 + j;
            }
        }
    }
    redZ[tid] = Zl; redN[tid] = Nl;
    __syncthreads();
    for (int s = 128; s > 0; s >>= 1) {
        if (tid < s) { redZ[tid] += redZ[tid + s]; redN[tid] += redN[tid + s]; }
        __syncthreads();
    }
    if (tid == 0) {
        float Z = redZ[0], num = redN[0];
        int neq = (int)(eqCount < (unsigned)EQ_CAP ? eqCount : (unsigned)EQ_CAP);
        int needed = knn - (int)cgt;
        if (needed > neq) needed = neq;
        for (int a = 1; a < neq; ++a) {
            int v = eqIdx[a]; int b2 = a - 1;
            while (b2 >= 0 && eqIdx[b2] > v) { eqIdx[b2 + 1] = eqIdx[b2]; --b2; }
            eqIdx[b2 + 1] = v;
        }
        unsigned tb = (tu & 0x8000u) ? (tu & 0x7FFFu) : ((~tu) & 0xFFFFu);
        float wt = __expf(bf2f((unsigned short)tb) * invT);
        for (int a = 0; a < needed; ++a) {
            Z += wt;
            if (qlabel[eqIdx[a]] == tgt) num += wt;
        }
        float gt = num / Z;
        if (gt > 1e-8f) atomicAdd(out0, -logf(gt) * (1.0f / (float)BN));
    }
}

// ---- dc gemm v6b: v5 + bijective XCD swizzle (resubmit; textual variant).
// Flat dispatch id fid (x-fastest) round-robins XCDs (xcd ~ fid%8). Remap so
// fid%8 == kslab%8: all 16 blocks of one K-slab (8 c-tiles x 2 m-tiles) land
// on ONE XCD -> E tiles 8-way L2-shared (temporally clustered), P 2-way.
// Staging drains become L2 hits instead of L3 round trips. Bounds audited:
// E max idx = 512*65536 exactly; P < 1000*65536; dct < 512*1024; LDS <= 64KB. ----
__global__ void __launch_bounds__(256, 2) dc_gemm(const unsigned short* __restrict__ E,
                                                  const float* __restrict__ P,
                                                  float* __restrict__ dct) {
    __shared__ unsigned short As[256 * 64];   // bf16, 256 m-rows of 64 (128B)
    __shared__ float Bsf[128 * 64];           // f32, 128 c-rows of 64 (256B)
    int tid = threadIdx.x;
    // fid = bx + 8*by + 16*bz in [0,512); inverse: kslab = fid%32,
    // rest = fid/32, ctile = rest%8, mtile = rest/8. Bijective.
    int fid = (int)blockIdx.x + (int)blockIdx.y * 8 + (int)blockIdx.z * 16;
    int kslab = fid % 32;
    int rest = fid / 32;
    int ctile = rest % 8;
    int mtile = rest / 8;
    int c0 = ctile * 128;
    int m0 = mtile * 256;
    int kb = kslab * (KN / 32);               // 2048-wide K slab
    int lane = tid & 63, w = tid >> 6;
    int l15 = lane & 15, quad = lane >> 4;
    int wm = w & 1, wn = w >> 1;
    // A staging: rows i*32+tr (8 of 256), 16B chunk chA of 8 per row
    int tr = tid >> 3, chA = tid & 7;
    int sa = (chA ^ (tr & 7)) << 3;           // ushort offset within row (swizzled src)
    // B staging: rows i*16+br (8 of 128), 16B chunk cb of 16 per row
    int br = tid >> 4, cbB = tid & 15;
    int sb = (cbB ^ (br & 7)) << 2;           // f32 offset within row (swizzled src)
    const int swr = l15 & 7;                  // read-side swizzle (row&7 == l15&7)
    f32x4 acc[2][4][4];
    #pragma unroll
    for (int mt = 0; mt < 2; ++mt)
        #pragma unroll
        for (int r = 0; r < 4; ++r)
            #pragma unroll
            for (int c = 0; c < 4; ++c)
                #pragma unroll
                for (int j = 0; j < 4; ++j) acc[mt][r][c][j] = 0.f;

    for (int kc = 0; kc < KN / 32; kc += 64) {
        // A tiles: 256x64 bf16, direct-to-LDS, pre-swizzled global source
        #pragma unroll
        for (int i = 0; i < 8; ++i) {
            int row = i * 32 + tr;
            async16(E + (size_t)(m0 + row) * KN + kb + kc + sa, &As[(i * 256 + tid) * 8]);
        }
        // B tile: 128x64 f32, direct-to-LDS, pre-swizzled global source.
        // Rows past CN-1 clamp to row CN-1; garbage lands in dct cols >=1000 (never read).
        #pragma unroll
        for (int i = 0; i < 8; ++i) {
            int gr = c0 + i * 16 + br;
            if (gr > CN - 1) gr = CN - 1;
            async16(P + (size_t)gr * KN + kb + kc + sb, &Bsf[(i * 256 + tid) * 4]);
        }
        __syncthreads();
        #pragma unroll
        for (int ks = 0; ks < 2; ++ks) {
            bf16x8 af[2][4], bfr[4];
            #pragma unroll
            for (int mt = 0; mt < 2; ++mt)
                #pragma unroll
                for (int r = 0; r < 4; ++r) {
                    int arow = mt * 128 + wm * 64 + r * 16 + l15;
                    af[mt][r] = *(const bf16x8*)&As[arow * 64 + (((ks * 4 + quad) ^ swr) << 3)];
                }
            #pragma unroll
            for (int c = 0; c < 4; ++c) {
                int brow = wn * 64 + c * 16 + l15;
                int ck = ks * 8 + quad * 2;
                float4 ra = *(const float4*)&Bsf[brow * 64 + ((ck ^ swr) << 2)];
                float4 rb = *(const float4*)&Bsf[brow * 64 + (((ck + 1) ^ swr) << 2)];
                uint4 pk;
                pk.x = cvtpk(ra.x, ra.y); pk.y = cvtpk(ra.z, ra.w);
                pk.z = cvtpk(rb.x, rb.y); pk.w = cvtpk(rb.z, rb.w);
                bfr[c] = *(bf16x8*)&pk;
            }
            #pragma unroll
            for (int mt = 0; mt < 2; ++mt)
                #pragma unroll
                for (int r = 0; r < 4; ++r)
                    #pragma unroll
                    for (int c = 0; c < 4; ++c)
                        acc[mt][r][c] = __builtin_amdgcn_mfma_f32_16x16x32_bf16(
                            af[mt][r], bfr[c], acc[mt][r][c], 0, 0, 0);
        }
        __syncthreads();
    }
    #pragma unroll
    for (int mt = 0; mt < 2; ++mt)
        #pragma unroll
        for (int r = 0; r < 4; ++r)
            #pragma unroll
            for (int reg = 0; reg < 4; ++reg) {
                int m = m0 + mt * 128 + wm * 64 + r * 16 + quad * 4 + reg;
                #pragma unroll
                for (int c = 0; c < 4; ++c) {
                    int cc = c0 + wn * 64 + c * 16 + l15;
                    atomicAdd(&dct[m * 1024 + cc], acc[mt][r][c][reg]);
                }
            }
}

// ---- log_softmax(q_logits), qmask, fc loss ----
__global__ void __launch_bounds__(256) logq_fc(const float* __restrict__ x_all,
                                               const int* __restrict__ target,
                                               float* __restrict__ logq,
                                               float* __restrict__ qmask,
                                               float* __restrict__ out1) {
    int row = blockIdx.x, tid = threadIdx.x;
    const float* x = x_all + (size_t)row * CN;
    __shared__ float red[256], red2[256];
    float mx = -INFINITY, mn = INFINITY;
    for (int c = tid; c < CN; c += 256) { float v = x[c]; mx = fmaxf(mx, v); mn = fminf(mn, v); }
    red[tid] = mx; red2[tid] = mn;
    __syncthreads();
    for (int s = 128; s > 0; s >>= 1) {
        if (tid < s) { red[tid] = fmaxf(red[tid], red[tid + s]); red2[tid] = fminf(red2[tid], red2[tid + s]); }
        __syncthreads();
    }
    mx = red[0]; mn = red2[0];
    __syncthreads();
    float se = 0.f, sx = 0.f;
    for (int c = tid; c < CN; c += 256) { float v = x[c]; se += __expf(v - mx); sx += v; }
    red[tid] = se; red2[tid] = sx;
    __syncthreads();
    for (int s = 128; s > 0; s >>= 1) {
        if (tid < s) { red[tid] += red[tid + s]; red2[tid] += red2[tid + s]; }
        __syncthreads();
    }
    float lse = mx + logf(red[0]);
    float sumlogq = red2[0] - (float)CN * lse;
    for (int c = tid; c < CN; c += 256) logq[(size_t)row * CN + c] = x[c] - lse;
    if (tid == 0) {
        float lqt = x[target[row]] - lse;
        bool qm = (mn - lse) > logf(1e-8f);
        qmask[row] = qm ? 1.0f : 0.0f;
        if (qm) {
            float fc = -(0.1f / 999.0f * (sumlogq - lqt) + 0.9f * lqt);
            atomicAdd(out1, fc * (1.0f / (float)BN));
        }
    }
}

// ---- dc loss ----
__global__ void __launch_bounds__(256) dc_loss(const float* __restrict__ dct,
                                               const float* __restrict__ logq,
                                               const float* __restrict__ qmask,
                                               const float* __restrict__ Z,
                                               float* __restrict__ out2) {
    int row = blockIdx.x, tid = threadIdx.x;
    __shared__ float red[256];
    float invZ = 1.0f / Z[row];
    float s = 0.f;
    for (int c = tid; c < CN; c += 256) {
        float T = dct[row * 1024 + c] * invZ;
        if (T > 0.f) s += T * (logf(T) - logq[(size_t)row * CN + c]);
    }
    red[tid] = s;
    __syncthreads();
    for (int st = 128; st > 0; st >>= 1) {
        if (tid < st) red[tid] += red[tid + st];
        __syncthreads();
    }
    if (tid == 0 && qmask[row] > 0.f)
        atomicAdd(out2, red[0] * (1.0f / (float)BN));
}

extern "C" void kernel_launch(void* const* d_in, const int* in_sizes, int n_in,
                              void* d_out, int out_size, void* d_ws, size_t ws_size,
                              hipStream_t stream) {
    (void)in_sizes; (void)n_in; (void)out_size;
    const float* norm_q   = (const float*)d_in[0];
    const float* q_logits = (const float*)d_in[1];
    const float* k_feat   = (const float*)d_in[2];
    const float* queue    = (const float*)d_in[4];
    const float* qlp      = (const float*)d_in[5];
    const int*   qlabel   = (const int*)d_in[6];
    const int*   target   = (const int*)d_in[7];
    const int*   knnp     = (const int*)d_in[8];
    float* out = (float*)d_out;
    char* ws = (char*)d_ws;

    const size_t SIM_B = 67108864;     // 512*65536*2
    const size_t QT_B  = 33554432;     // 65536*256*2
    const size_t AC_B  = 524288;       // 1024*256*2
    const size_t FUSED_NEED = SIM_B * 2 + QT_B + AC_B + 2097152 + 2048 + 2048000 + 2048;
    bool fused = (ws_size >= FUSED_NEED);

    unsigned short *simBF, *Ebf, *queueT, *Acat;
    float *dct, *Zb, *logq, *qmask;
    if (fused) {
        simBF  = (unsigned short*)(ws);
        Ebf    = (unsigned short*)(ws + SIM_B);
        queueT = (unsigned short*)(ws + 2 * SIM_B);
        Acat   = (unsigned short*)(ws + 2 * SIM_B + QT_B);
        dct    = (float*)(ws + 2 * SIM_B + QT_B + AC_B);
    } else {
        simBF  = (unsigned short*)(ws);
        Ebf    = simBF;   // overlay: supcon consumes simBF before E is written
        queueT = (unsigned short*)(ws + SIM_B);
        Acat   = (unsigned short*)(ws + SIM_B + QT_B);
        dct    = (float*)(ws + SIM_B + QT_B + AC_B);
    }
    Zb    = (float*)((char*)dct + 2097152);
    logq  = (float*)((char*)Zb + 2048);
    qmask = (float*)((char*)logq + 2048000);

    hipMemsetAsync(dct, 0, 2097152 + 2048, stream);   // dct + Zb
    hipMemsetAsync(d_out, 0, 3 * sizeof(float), stream);

    cvt_bf16<<<dim3(128), 256, 0, stream>>>(norm_q, Acat);
    cvt_bf16<<<dim3(128), 256, 0, stream>>>(k_feat, Acat + (size_t)BN * DN);
    transpose_q<<<dim3(KN / 64, 4), 256, 0, stream>>>(queue, queueT);

    if (fused) {
        gemm_sim<<<dim3(KN / 128, 8), 256, 0, stream>>>(Acat, queueT, simBF, Ebf, Zb, 4);
        supcon<<<dim3(BN), 256, 0, stream>>>(simBF, qlabel, target, knnp, out + 0);
    } else {
        gemm_sim<<<dim3(KN / 128, 4), 256, 0, stream>>>(Acat, queueT, simBF, nullptr, nullptr, 4);
        supcon<<<dim3(BN), 256, 0, stream>>>(simBF, qlabel, target, knnp, out + 0);
        gemm_sim<<<dim3(KN / 128, 4), 256, 0, stream>>>(Acat + (size_t)BN * DN, queueT,
                                                        nullptr, Ebf, Zb, 0);
    }
    dc_gemm<<<dim3(8, 2, 32), 256, 0, stream>>>(Ebf, qlp, dct);
    logq_fc<<<dim3(BN), 256, 0, stream>>>(q_logits, target, logq, qmask, out + 1);
    dc_loss<<<dim3(BN), 256, 0, stream>>>(dct, logq, qmask, Zb, out + 2);
}